// Round 5
// baseline (77.275 us; speedup 1.0000x reference)
//
#include <hip/hip_runtime.h>
#include <hip/hip_bf16.h>

#define KW    7
#define PADW  3
#define HW    56
#define ROWS  8
#define TILE_H (ROWS + KW - 1)   // 14
#define TILE_W 64                // 62 used, padded stride
#define NTHREADS 448             // 8 rows * 56 cols = 7 waves
#define NCHUNK 7                 // 56 / ROWS

#define LOG2E 1.44269504088896340736f

typedef float f2 __attribute__((ext_vector_type(2)));

__global__ __launch_bounds__(NTHREADS) void saconv_kernel(
    const float* __restrict__ x,
    const float* __restrict__ r,
    const float* __restrict__ Wq,
    const float* __restrict__ Wk,
    const float* __restrict__ Wv,
    const float* __restrict__ Wr,
    const float* __restrict__ up,
    const float* __restrict__ vp,
    float* __restrict__ out)
{
    // Two group-planes packed per LDS slot: v_pk_* processes both at one issue.
    __shared__ f2 xs[TILE_H][TILE_W];
    __shared__ f2 ro2[KW * KW];

    const int tid   = threadIdx.x;
    const int bid   = blockIdx.x;
    const int chunk = bid % NCHUNK;
    const int gp    = (bid / NCHUNK) & 31;   // group pair index
    const int b     = bid / (NCHUNK * 32);
    const int y0    = chunk * ROWS;
    const int g0    = 2 * gp;
    const int g1    = 2 * gp + 1;

    // per-group scalars for both planes
    const f2 wq2 = {Wq[g0], Wq[g1]};
    const f2 wk2 = {Wk[g0], Wk[g1]};
    const f2 wv2 = {Wv[g0], Wv[g1]};
    const f2 ug2 = {up[g0], up[g1]};
    const f2 vg2 = {vp[g0], vp[g1]};

    // r_o[g][pos] = sum_c r[(g*4+c), pos] * Wr[g*4+c]  (pos = i*7+j, row-major)
    if (tid < KW * KW) {
        float a0 = 0.f, a1 = 0.f;
#pragma unroll
        for (int c = 0; c < 4; ++c) {
            a0 += r[(g0 * 4 + c) * (KW * KW) + tid] * Wr[g0 * 4 + c];
            a1 += r[(g1 * 4 + c) * (KW * KW) + tid] * Wr[g1 * 4 + c];
        }
        f2 t; t.x = a0; t.y = a1;
        ro2[tid] = t;
    }

    // stage padded tiles of BOTH planes: rows [y0-3, y0+10], cols [-3, 58]
    const float* xb0 = x + (size_t)(b * 64 + g0) * (HW * HW);
    const float* xb1 = xb0 + HW * HW;
    for (int idx = tid; idx < TILE_H * 62; idx += NTHREADS) {
        const int ty = idx / 62;
        const int tx = idx - ty * 62;
        const int gy = y0 - PADW + ty;
        const int gx = tx - PADW;
        f2 v = {0.f, 0.f};
        if (gy >= 0 && gy < HW && gx >= 0 && gx < HW) {
            v.x = xb0[gy * HW + gx];
            v.y = xb1[gy * HW + gx];
        }
        xs[ty][tx] = v;
    }
    __syncthreads();

    const int row = tid / HW;        // 0..7
    const int col = tid - row * HW;  // 0..55

    // exp(l) = exp2(l*log2e), log2e folded into the per-thread packed constants.
    const f2 xc  = xs[row + PADW][col + PADW];
    const f2 q   = xc * wq2;
    const f2 a2  = (q + ug2) * wk2 * (f2){LOG2E, LOG2E};
    const f2 cc2 = (q + vg2) * (f2){LOG2E, LOG2E};

    // softmax over 49 taps for both group-planes at once.
    // Padding taps stay in the softmax: xv=0 there, logit = cc*ro[pos] (matches ref).
    f2 se = {0.f, 0.f}, sx = {0.f, 0.f};
#pragma unroll
    for (int i = 0; i < KW; ++i) {
#pragma unroll
        for (int j = 0; j < KW; ++j) {
            const f2 xv = xs[row + i][col + j];          // ds_read_b64
            const f2 l2 = a2 * xv + cc2 * ro2[i * KW + j]; // v_pk_mul + v_pk_fma
            f2 e;
            e.x = __builtin_amdgcn_exp2f(l2.x);          // v_exp_f32
            e.y = __builtin_amdgcn_exp2f(l2.y);
            se += e;                                     // v_pk_add
            sx = e * xv + sx;                            // v_pk_fma
        }
    }

    f2 o;
    o.x = wv2.x * sx.x * __builtin_amdgcn_rcpf(se.x);
    o.y = wv2.y * sx.y * __builtin_amdgcn_rcpf(se.y);

    const size_t base = ((size_t)(b * 64 + g0) * HW + (y0 + row)) * HW + col;
    out[base] = o.x;
    out[base + (size_t)HW * HW] = o.y;
}

extern "C" void kernel_launch(void* const* d_in, const int* in_sizes, int n_in,
                              void* d_out, int out_size, void* d_ws, size_t ws_size,
                              hipStream_t stream) {
    const float* x  = (const float*)d_in[0];
    const float* r  = (const float*)d_in[1];
    const float* Wq = (const float*)d_in[2];
    const float* Wk = (const float*)d_in[3];
    const float* Wv = (const float*)d_in[4];
    const float* Wr = (const float*)d_in[5];
    const float* up = (const float*)d_in[6];
    const float* vp = (const float*)d_in[7];
    float* out = (float*)d_out;

    const int grid = 4 * 32 * NCHUNK;  // B * (G/2) * chunks = 896
    saconv_kernel<<<grid, NTHREADS, 0, stream>>>(x, r, Wq, Wk, Wv, Wr, up, vp, out);
}